// Round 7
// baseline (215.591 us; speedup 1.0000x reference)
//
#include <hip/hip_runtime.h>
#include <cstdint>

// CamPoseNet: bit-faithful JAX threefry replication (validated rounds 1-6).
// Round 7: per-row constant hoisting + 2x in-lane t-unroll.
//  - lam/sgi/sig were recomputed EVERY DRAW (3 fdiv + 3 sqrt on the
//    quarter-rate trans pipe); now computed once per row at acquisition
//    (same ops, same order -> bit-identical values).
//  - each iteration evaluates draws (t, t+1) back-to-back: two independent
//    ~130-cycle chains interleave -> ~2x ILP at 2 waves/SIMD (GRID=512,
//    rows/lane=8 keeps the tail at its best point ~1.33x). Accept priority
//    t before t+1 preserves the reference's first-accept semantics.
//  - inline E^T epilogue (q prefetched at row-grab); LDS queue + chain
//    producer wave + watermark as before.
// All float ops on the accept-decision path use __f*_rn intrinsics (no FMA
// contraction) - matches XLA:CPU strict mul/add. Do not alter any arithmetic.

#define DEVI __device__ __forceinline__
#define MAXT 96
#define GRID 512
#define NT 256

DEVI uint32_t rotl32(uint32_t v, int s) { return (v << s) | (v >> (32 - s)); }

// Threefry-2x32, 20 rounds (jax._src.prng.threefry2x32).
DEVI void tf2x32(uint32_t k0, uint32_t k1, uint32_t x0, uint32_t x1,
                 uint32_t& o0, uint32_t& o1) {
  const uint32_t kx = k0 ^ k1 ^ 0x1BD11BDAu;
  x0 += k0; x1 += k1;
#define TFR(r) x0 += x1; x1 = rotl32(x1, (r)); x1 ^= x0;
  TFR(13) TFR(15) TFR(26) TFR(6)
  x0 += k1; x1 += kx + 1u;
  TFR(17) TFR(29) TFR(16) TFR(24)
  x0 += kx; x1 += k0 + 2u;
  TFR(13) TFR(15) TFR(26) TFR(6)
  x0 += k0; x1 += k1 + 3u;
  TFR(17) TFR(29) TFR(16) TFR(24)
  x0 += k1; x1 += kx + 4u;
  TFR(13) TFR(15) TFR(26) TFR(6)
  x0 += kx; x1 += k0 + 5u;
#undef TFR
  o0 = x0; o1 = x1;
}

// XLA:CPU Cephes-style f32 log, strict mul/add. x > 0, normal.
DEVI float xla_logf_pos(float xf) {
  uint32_t bits = __float_as_uint(xf);
  float e = (float)((int)(bits >> 23) - 126);
  float m = __uint_as_float((bits & 0x007fffffu) | 0x3f000000u);  // [0.5,1)
  if (m < 0.70710678118654752440f) {
    e = __fsub_rn(e, 1.0f);
    m = __fadd_rn(__fsub_rn(m, 1.0f), m);
  } else {
    m = __fsub_rn(m, 1.0f);
  }
  float z = __fmul_rn(m, m);
  float y = 7.0376836292e-2f;
  y = __fadd_rn(__fmul_rn(y, m), -1.1514610310e-1f);
  y = __fadd_rn(__fmul_rn(y, m),  1.1676998740e-1f);
  y = __fadd_rn(__fmul_rn(y, m), -1.2420140846e-1f);
  y = __fadd_rn(__fmul_rn(y, m),  1.4249322787e-1f);
  y = __fadd_rn(__fmul_rn(y, m), -1.6668057665e-1f);
  y = __fadd_rn(__fmul_rn(y, m),  2.0000714765e-1f);
  y = __fadd_rn(__fmul_rn(y, m), -2.4999993993e-1f);
  y = __fadd_rn(__fmul_rn(y, m),  3.3333331174e-1f);
  y = __fmul_rn(y, m);
  y = __fmul_rn(y, z);
  y = __fadd_rn(y, __fmul_rn(e, -2.12194440e-4f));
  y = __fsub_rn(y, __fmul_rn(z, 0.5f));
  float r = __fadd_rn(m, y);
  r = __fadd_rn(r, __fmul_rn(e, 0.693359375f));
  return r;
}

// XLA EmitLog1p, select form (bit-identical per lane to the branchy version)
DEVI float xla_log1pf(float v) {
  float small = __fmul_rn(__fadd_rn(__fmul_rn(-0.5f, v), 1.0f), v);
  float big = xla_logf_pos(__fadd_rn(v, 1.0f));
  return (fabsf(v) < 1e-4f) ? small : big;
}

// XLA ErfInv32, coefficient-select form: identical op sequence per lane as
// the taken branch -> bit-exact, no dual-path exec-mask waste.
DEVI float xla_erfinvf(float x) {
  float w = -xla_log1pf(-__fmul_rn(x, x));
  bool c = (w < 5.0f);
  float qc = __fsub_rn(w, 2.5f);
  float qr = __fsub_rn(sqrtf(w), 3.0f);
  float q = c ? qc : qr;
  float p =                          c ? 2.81022636e-08f : -0.000200214257f;
  p = __fadd_rn(__fmul_rn(p, q), c ?  3.43273939e-07f :  0.000100950558f);
  p = __fadd_rn(__fmul_rn(p, q), c ? -3.5233877e-06f  :  0.00134934322f);
  p = __fadd_rn(__fmul_rn(p, q), c ? -4.39150654e-06f : -0.00367342844f);
  p = __fadd_rn(__fmul_rn(p, q), c ?  0.00021858087f  :  0.00573950773f);
  p = __fadd_rn(__fmul_rn(p, q), c ? -0.00125372503f  : -0.0076224613f);
  p = __fadd_rn(__fmul_rn(p, q), c ? -0.00417768164f  :  0.00943887047f);
  p = __fadd_rn(__fmul_rn(p, q), c ?  0.246640727f    :  1.00167406f);
  p = __fadd_rn(__fmul_rn(p, q), c ?  1.50140941f     :  2.83297682f);
  return __fmul_rn(p, x);
}

DEVI float u01_from_bits(uint32_t bits) {
  return __fsub_rn(__uint_as_float(0x3f800000u | (bits >> 9)), 1.0f);
}

// One full rejection draw at (row r, subkeys ck): produces y[4] and accept.
// Per-row constants passed in registers (hoisted). Bit-identical to R1-R6.
DEVI void draw_eval(uint4 ck, uint32_t r,
                    float lam1, float lam2, float lam3,
                    float sgi1, float sgi2, float sgi3,
                    float sig0, float sig1, float sig2, float sig3,
                    float sgi0,
                    float& y0, float& y1, float& y2, float& y3,
                    bool& accept) {
  const uint32_t base = r * 4u;
  float nv[4];
#pragma unroll
  for (int j = 0; j < 4; ++j) {
    uint32_t o0, o1;
    tf2x32(ck.x, ck.y, 0u, base + (uint32_t)j, o0, o1);
    float u = u01_from_bits(o0 ^ o1);
    float xin = __fadd_rn(__fmul_rn(u, 2.0f), -0.99999994f);
    xin = fmaxf(-0.99999994f, xin);
    nv[j] = __fmul_rn(1.41421356237309504880f, xla_erfinvf(xin));
  }

  uint32_t uo0, uo1;
  tf2x32(ck.z, ck.w, 0u, r, uo0, uo1);
  float uu = u01_from_bits(uo0 ^ uo1);

  y0 = __fmul_rn(nv[0], sig0);
  y1 = __fmul_rn(nv[1], sig1);
  y2 = __fmul_rn(nv[2], sig2);
  y3 = __fmul_rn(nv[3], sig3);

  float n2 = __fmul_rn(y0, y0);
  n2 = __fadd_rn(n2, __fmul_rn(y1, y1));
  n2 = __fadd_rn(n2, __fmul_rn(y2, y2));
  n2 = __fadd_rn(n2, __fmul_rn(y3, y3));
  float nr = sqrtf(n2);
  y0 = __fdiv_rn(y0, nr); y1 = __fdiv_rn(y1, nr);
  y2 = __fdiv_rn(y2, nr); y3 = __fdiv_rn(y3, nr);

  float s0q = __fmul_rn(y0, y0), s1q = __fmul_rn(y1, y1);
  float s2q = __fmul_rn(y2, y2), s3q = __fmul_rn(y3, y3);

  float s1 = __fmul_rn(s0q, 1e-6f);
  s1 = __fadd_rn(s1, __fmul_rn(s1q, lam1));
  s1 = __fadd_rn(s1, __fmul_rn(s2q, lam2));
  s1 = __fadd_rn(s1, __fmul_rn(s3q, lam3));

  float s2 = __fmul_rn(s0q, sgi0);
  s2 = __fadd_rn(s2, __fmul_rn(s1q, sgi1));
  s2 = __fadd_rn(s2, __fmul_rn(s2q, sgi2));
  s2 = __fadd_rn(s2, __fmul_rn(s3q, sgi3));

  float lr = __fsub_rn(-s1, 2.7725887298583984f);  // 2*f32(ln 4)
  lr = __fadd_rn(lr, 1.5f);
  lr = __fadd_rn(lr, __fmul_rn(2.0f, xla_logf_pos(s2)));

  float lu = (uu > 0.0f) ? xla_logf_pos(uu) : -__builtin_inff();
  accept = (lu < lr);
}

// ---------------------------------------------------------------------------
__global__ __launch_bounds__(256) void campose_kernel(
    const float* __restrict__ q, const float* __restrict__ Z,
    float* __restrict__ out, const int* __restrict__ seedp, int N, int C) {
  __shared__ uint4 chain[MAXT + 4];
  __shared__ uint32_t next_row;
  __shared__ uint32_t wm;   // watermark: # of published chain entries

  const int tid = threadIdx.x;
  const int rbeg = blockIdx.x * C;
  const int rend = min(N, rbeg + C);
  if (tid == 0) { next_row = (uint32_t)(rbeg + 192); wm = 0u; }
  __syncthreads();

  const int wave = tid >> 6;
  if (wave == 0) {
    // Producer: lanes 0-2 of wave 0 walk the split() chain; publish each
    // entry with a release watermark. Other waves consume concurrently.
    int lane = tid & 63;
    uint32_t ka = 0u, kb = (uint32_t)seedp[0];
    uint32_t x1i = (lane == 2) ? 0u : (uint32_t)(lane + 1);
    for (int t = 0; t < MAXT; ++t) {
      uint32_t o0 = 0u, o1 = 0u;
      if (lane < 3) tf2x32(ka, kb, 0u, x1i, o0, o1);
      uint32_t s1a = __shfl(o0, 0, 64), s1b = __shfl(o1, 0, 64);
      uint32_t s2a = __shfl(o0, 1, 64), s2b = __shfl(o1, 1, 64);
      if (lane == 0) chain[t] = make_uint4(s1a, s1b, s2a, s2b);
      ka = __shfl(o0, 2, 64); kb = __shfl(o1, 2, 64);
      __threadfence_block();
      if (lane == 0) *(volatile uint32_t*)&wm = (uint32_t)(t + 1);
    }
    if (lane == 0) {
      chain[MAXT]     = make_uint4(0u, 0u, 0u, 0u);   // prefetch pads
      chain[MAXT + 1] = make_uint4(0u, 0u, 0u, 0u);
      chain[MAXT + 2] = make_uint4(0u, 0u, 0u, 0u);
      chain[MAXT + 3] = make_uint4(0u, 0u, 0u, 0u);
    }
    __threadfence_block();
    if (lane == 0) *(volatile uint32_t*)&wm = (uint32_t)(MAXT + 4);
  }

  const float sgi0 = __fadd_rn(1.0f, __fmul_rn(2.0f, 1e-6f));
  const float sig0 = sqrtf(__fdiv_rn(1.0f, sgi0));

  // --- per-lane row state: current row r + pre-grabbed next row rn ---
  int r, rn;
  if (wave == 0) {
    r  = (int)atomicAdd(&next_row, 1u);   // producer wave joins late; queue
    rn = (int)atomicAdd(&next_row, 1u);   // auto-balances
  } else {
    r  = rbeg + (tid - 64);               // static first 192 rows
    rn = (int)atomicAdd(&next_row, 1u);
  }
  bool have = (r < rend);
  float Zn0 = 0, Zn1 = 0, Zn2 = 0;
  float4 qc = make_float4(0, 0, 0, 0), qn = make_float4(0, 0, 0, 0);
  // hoisted per-row constants for the CURRENT row
  float lam1 = 0, lam2 = 0, lam3 = 0, sgi1 = 1, sgi2 = 1, sgi3 = 1;
  float sig1 = 1, sig2 = 1, sig3 = 1;
  if (have) {
    float Z0 = Z[r * 3 + 0], Z1 = Z[r * 3 + 1], Z2 = Z[r * 3 + 2];
    lam1 = -Z0; lam2 = -Z1; lam3 = -Z2;
    sgi1 = __fadd_rn(1.0f, __fmul_rn(2.0f, lam1));
    sgi2 = __fadd_rn(1.0f, __fmul_rn(2.0f, lam2));
    sgi3 = __fadd_rn(1.0f, __fmul_rn(2.0f, lam3));
    sig1 = sqrtf(__fdiv_rn(1.0f, sgi1));
    sig2 = sqrtf(__fdiv_rn(1.0f, sgi2));
    sig3 = sqrtf(__fdiv_rn(1.0f, sgi3));
    qc = *reinterpret_cast<const float4*>(q + (size_t)r * 4);
  }
  if (rn < rend) {
    Zn0 = Z[rn * 3 + 0]; Zn1 = Z[rn * 3 + 1]; Zn2 = Z[rn * 3 + 2];
    qn = *reinterpret_cast<const float4*>(q + (size_t)rn * 4);
  }

  // wait for chain[0..1]; cache them (reused at every accept)
  uint32_t wml = *(volatile uint32_t*)&wm;
  while (wml < 2u) wml = *(volatile uint32_t*)&wm;
  __threadfence_block();
  const uint4 ck0 = chain[0];
  const uint4 ck1 = chain[1];
  uint4 ckA = ck0, ckB = ck1;
  bool chain_all = (wml >= (uint32_t)(MAXT + 4));
  int t = 0;

  while (__ballot(have)) {
    if (have) {
      // prefetch the next t-pair's subkeys (full iteration of slack)
      if (!chain_all) {
        uint32_t need = (uint32_t)(t + 4);
        uint32_t w_ = *(volatile uint32_t*)&wm;
        while (w_ < need) w_ = *(volatile uint32_t*)&wm;
        __threadfence_block();
        chain_all = (w_ >= (uint32_t)(MAXT + 4));
      }
      uint4 ckn0 = chain[t + 2];
      uint4 ckn1 = chain[t + 3];

      // two independent draws: (r, t) and (r, t+1) — scheduler interleaves
      float a0y0, a0y1, a0y2, a0y3; bool a0;
      float b0y0, b0y1, b0y2, b0y3; bool a1;
      draw_eval(ckA, (uint32_t)r, lam1, lam2, lam3, sgi1, sgi2, sgi3,
                sig0, sig1, sig2, sig3, sgi0, a0y0, a0y1, a0y2, a0y3, a0);
      draw_eval(ckB, (uint32_t)r, lam1, lam2, lam3, sgi1, sgi2, sgi3,
                sig0, sig1, sig2, sig3, sgi0, b0y0, b0y1, b0y2, b0y3, a1);

      bool adv = a0 | a1 | ((t + 2) >= MAXT);
      if (adv) {
        // first-accept priority: slot0 (t) before slot1 (t+1)
        float y0 = a0 ? a0y0 : b0y0;
        float y1 = a0 ? a0y1 : b0y1;
        float y2v = a0 ? a0y2 : b0y2;
        float y3 = a0 ? a0y3 : b0y3;

        // inline epilogue: qn = q/||q||, out = E^T y
        float a = qc.x, b = qc.y, c = qc.z, d = qc.w;
        float qn2 = __fmul_rn(a, a);
        qn2 = __fadd_rn(qn2, __fmul_rn(b, b));
        qn2 = __fadd_rn(qn2, __fmul_rn(c, c));
        qn2 = __fadd_rn(qn2, __fmul_rn(d, d));
        float qnr = sqrtf(qn2);
        a = __fdiv_rn(a, qnr); b = __fdiv_rn(b, qnr);
        c = __fdiv_rn(c, qnr); d = __fdiv_rn(d, qnr);

        float o0v = __fadd_rn(__fadd_rn(__fadd_rn(__fmul_rn(a, y0), __fmul_rn(b, y1)),
                                        __fmul_rn(c, y2v)), __fmul_rn(d, y3));
        float o1v = __fadd_rn(__fadd_rn(__fadd_rn(__fmul_rn(-b, y0), __fmul_rn(a, y1)),
                                        __fmul_rn(-d, y2v)), __fmul_rn(c, y3));
        float o2v = __fadd_rn(__fadd_rn(__fadd_rn(__fmul_rn(-c, y0), __fmul_rn(d, y1)),
                                        __fmul_rn(a, y2v)), __fmul_rn(-b, y3));
        float o3v = __fadd_rn(__fadd_rn(__fadd_rn(__fmul_rn(d, y0), __fmul_rn(c, y1)),
                                        __fmul_rn(-b, y2v)), __fmul_rn(-a, y3));
        *reinterpret_cast<float4*>(out + (size_t)r * 4) =
            make_float4(o0v, o1v, o2v, o3v);

        // rotate in the pre-grabbed row; compute its constants (same ops,
        // same order as reference -> bit-identical); pre-grab the next one
        r = rn; qc = qn;
        lam1 = -Zn0; lam2 = -Zn1; lam3 = -Zn2;
        sgi1 = __fadd_rn(1.0f, __fmul_rn(2.0f, lam1));
        sgi2 = __fadd_rn(1.0f, __fmul_rn(2.0f, lam2));
        sgi3 = __fadd_rn(1.0f, __fmul_rn(2.0f, lam3));
        sig1 = sqrtf(__fdiv_rn(1.0f, sgi1));
        sig2 = sqrtf(__fdiv_rn(1.0f, sgi2));
        sig3 = sqrtf(__fdiv_rn(1.0f, sgi3));
        t = 0;
        ckA = ck0; ckB = ck1;
        have = (r < rend);
        rn = (int)atomicAdd(&next_row, 1u);
        if (rn < rend) {
          Zn0 = Z[rn * 3 + 0]; Zn1 = Z[rn * 3 + 1]; Zn2 = Z[rn * 3 + 2];
          qn = *reinterpret_cast<const float4*>(q + (size_t)rn * 4);
        }
      } else {
        t += 2;
        ckA = ckn0; ckB = ckn1;
      }
    }
  }
}

extern "C" void kernel_launch(void* const* d_in, const int* in_sizes, int n_in,
                              void* d_out, int out_size, void* d_ws, size_t ws_size,
                              hipStream_t stream) {
  const float* q = (const float*)d_in[0];
  const float* Z = (const float*)d_in[1];
  const int* seed = (const int*)d_in[2];
  float* out = (float*)d_out;
  int N = in_sizes[0] / 4;

  int C = (N + GRID - 1) / GRID;  // rows per block (contiguous chunk)
  campose_kernel<<<GRID, NT, 0, stream>>>(q, Z, out, seed, N, C);
}

// Round 8
// 203.938 us; speedup vs baseline: 1.0571x; 1.0571x over previous
//
#include <hip/hip_runtime.h>
#include <cstdint>

// CamPoseNet: bit-faithful JAX threefry replication (validated rounds 1-7).
// Round 8: source-level ILP - array-of-chains draw evaluation.
//  R7 showed the compiler serializes independent draw_eval calls (VGPR 56,
//  VALUBusy pinned at ~53% = 1 inst/~7.5cyc/wave, pure dependency-latency).
//  One draw already contains 5 independent threefry chains (4 normals + 1
//  uniform) and 4 independent erfinv chains; this round writes them in SoA
//  form: every threefry round / poly step is an unrolled j-loop, so the
//  natural schedule interleaves 4-5 chains and dependency stalls vanish at
//  2 waves/SIMD. Per-element ops and order unchanged -> bit-identical.
//  Structure: GRID=512 (8 rows/lane, tail 1.33x), LDS row queue, in-kernel
//  chain producer, row pre-grab, inline E^T epilogue (best of R5/R6).
// All float ops on the accept-decision path use __f*_rn intrinsics (no FMA
// contraction) - matches XLA:CPU strict mul/add. Do not alter any arithmetic.

#define DEVI __device__ __forceinline__
#define MAXT 96
#define GRID 512
#define NT 256

DEVI uint32_t rotl32(uint32_t v, int s) { return (v << s) | (v >> (32 - s)); }

// Threefry-2x32, 20 rounds - single-chain version (producer wave only).
DEVI void tf2x32(uint32_t k0, uint32_t k1, uint32_t x0, uint32_t x1,
                 uint32_t& o0, uint32_t& o1) {
  const uint32_t kx = k0 ^ k1 ^ 0x1BD11BDAu;
  x0 += k0; x1 += k1;
#define TFR(r) x0 += x1; x1 = rotl32(x1, (r)); x1 ^= x0;
  TFR(13) TFR(15) TFR(26) TFR(6)
  x0 += k1; x1 += kx + 1u;
  TFR(17) TFR(29) TFR(16) TFR(24)
  x0 += kx; x1 += k0 + 2u;
  TFR(13) TFR(15) TFR(26) TFR(6)
  x0 += k0; x1 += k1 + 3u;
  TFR(17) TFR(29) TFR(16) TFR(24)
  x0 += k1; x1 += kx + 4u;
  TFR(13) TFR(15) TFR(26) TFR(6)
  x0 += kx; x1 += k0 + 5u;
#undef TFR
  o0 = x0; o1 = x1;
}

DEVI float u01_from_bits(uint32_t bits) {
  return __fsub_rn(__uint_as_float(0x3f800000u | (bits >> 9)), 1.0f);
}

// 2-wide interleaved XLA:CPU Cephes log (x > 0). Per-element ops identical
// to the scalar version - textual interleave only.
DEVI void xla_logf_pos2(float xa, float xb, float& ra, float& rb) {
  uint32_t ba = __float_as_uint(xa), bb = __float_as_uint(xb);
  float ea = (float)((int)(ba >> 23) - 126);
  float eb = (float)((int)(bb >> 23) - 126);
  float ma = __uint_as_float((ba & 0x007fffffu) | 0x3f000000u);
  float mb = __uint_as_float((bb & 0x007fffffu) | 0x3f000000u);
  bool la = ma < 0.70710678118654752440f;
  bool lb = mb < 0.70710678118654752440f;
  ea = la ? __fsub_rn(ea, 1.0f) : ea;
  eb = lb ? __fsub_rn(eb, 1.0f) : eb;
  ma = la ? __fadd_rn(__fsub_rn(ma, 1.0f), ma) : __fsub_rn(ma, 1.0f);
  mb = lb ? __fadd_rn(__fsub_rn(mb, 1.0f), mb) : __fsub_rn(mb, 1.0f);
  float za = __fmul_rn(ma, ma), zb = __fmul_rn(mb, mb);
  float ya = 7.0376836292e-2f, yb = 7.0376836292e-2f;
  const float LC[8] = {-1.1514610310e-1f, 1.1676998740e-1f, -1.2420140846e-1f,
                       1.4249322787e-1f, -1.6668057665e-1f, 2.0000714765e-1f,
                       -2.4999993993e-1f, 3.3333331174e-1f};
#pragma unroll
  for (int s = 0; s < 8; ++s) {
    ya = __fadd_rn(__fmul_rn(ya, ma), LC[s]);
    yb = __fadd_rn(__fmul_rn(yb, mb), LC[s]);
  }
  ya = __fmul_rn(ya, ma); yb = __fmul_rn(yb, mb);
  ya = __fmul_rn(ya, za); yb = __fmul_rn(yb, zb);
  ya = __fadd_rn(ya, __fmul_rn(ea, -2.12194440e-4f));
  yb = __fadd_rn(yb, __fmul_rn(eb, -2.12194440e-4f));
  ya = __fsub_rn(ya, __fmul_rn(za, 0.5f));
  yb = __fsub_rn(yb, __fmul_rn(zb, 0.5f));
  ra = __fadd_rn(__fadd_rn(ma, ya), __fmul_rn(ea, 0.693359375f));
  rb = __fadd_rn(__fadd_rn(mb, yb), __fmul_rn(eb, 0.693359375f));
}

// One full rejection draw, 5-way/4-way interleaved (SoA over chains).
// Bit-identical per element to the scalar pipeline of rounds 1-7.
DEVI void draw_eval(const uint4 ck, uint32_t r,
                    float lam1, float lam2, float lam3,
                    float sgi0, float sgi1, float sgi2, float sgi3,
                    float sig0, float sig1, float sig2, float sig3,
                    float& ry0, float& ry1, float& ry2, float& ry3,
                    bool& accept) {
  const uint32_t base = r * 4u;
  // ---- 5 interleaved threefry chains: j<4 normals (key ck.xy, ctr base+j),
  //      j==4 uniform (key ck.zw, ctr r) ----
  const uint32_t kA = ck.x, kB = ck.y, kX = kA ^ kB ^ 0x1BD11BDAu;
  const uint32_t kC = ck.z, kD = ck.w, kY = kC ^ kD ^ 0x1BD11BDAu;
  uint32_t x0[5], x1[5];
#pragma unroll
  for (int j = 0; j < 4; ++j) { x0[j] = kA; x1[j] = (base + (uint32_t)j) + kB; }
  x0[4] = kC; x1[4] = r + kD;
#define RND(rot) { \
  _Pragma("unroll") for (int j = 0; j < 5; ++j) x0[j] += x1[j]; \
  _Pragma("unroll") for (int j = 0; j < 5; ++j) x1[j] = rotl32(x1[j], rot); \
  _Pragma("unroll") for (int j = 0; j < 5; ++j) x1[j] ^= x0[j]; }
#define INJ(a0, a1, b0, b1, c) { \
  _Pragma("unroll") for (int j = 0; j < 4; ++j) { x0[j] += a0; x1[j] += b0 + c; } \
  x0[4] += a1; x1[4] += b1 + c; }
  RND(13) RND(15) RND(26) RND(6)
  INJ(kB, kD, kX, kY, 1u)
  RND(17) RND(29) RND(16) RND(24)
  INJ(kX, kY, kA, kC, 2u)
  RND(13) RND(15) RND(26) RND(6)
  INJ(kA, kC, kB, kD, 3u)
  RND(17) RND(29) RND(16) RND(24)
  INJ(kB, kD, kX, kY, 4u)
  RND(13) RND(15) RND(26) RND(6)
  INJ(kX, kY, kA, kC, 5u)
#undef RND
#undef INJ
  uint32_t bz[5];
#pragma unroll
  for (int j = 0; j < 5; ++j) bz[j] = x0[j] ^ x1[j];
  float uu = u01_from_bits(bz[4]);

  // ---- normals: u -> xin (uniform(-0.99999994, 1)) ----
  float xin[4];
#pragma unroll
  for (int j = 0; j < 4; ++j) {
    float u = u01_from_bits(bz[j]);
    float xv = __fadd_rn(__fmul_rn(u, 2.0f), -0.99999994f);
    xin[j] = fmaxf(-0.99999994f, xv);
  }

  // ---- 4-way interleaved erfinv: w = -log1p(-x^2) ----
  float v[4], w[4];
#pragma unroll
  for (int j = 0; j < 4; ++j) v[j] = -__fmul_rn(xin[j], xin[j]);
  float e[4], m[4];
#pragma unroll
  for (int j = 0; j < 4; ++j) {
    uint32_t b_ = __float_as_uint(__fadd_rn(v[j], 1.0f));
    e[j] = (float)((int)(b_ >> 23) - 126);
    m[j] = __uint_as_float((b_ & 0x007fffffu) | 0x3f000000u);
  }
#pragma unroll
  for (int j = 0; j < 4; ++j) {
    bool lt = m[j] < 0.70710678118654752440f;
    e[j] = lt ? __fsub_rn(e[j], 1.0f) : e[j];
    m[j] = lt ? __fadd_rn(__fsub_rn(m[j], 1.0f), m[j]) : __fsub_rn(m[j], 1.0f);
  }
  float zz[4], yy[4];
#pragma unroll
  for (int j = 0; j < 4; ++j) zz[j] = __fmul_rn(m[j], m[j]);
#pragma unroll
  for (int j = 0; j < 4; ++j) yy[j] = 7.0376836292e-2f;
  const float LC[8] = {-1.1514610310e-1f, 1.1676998740e-1f, -1.2420140846e-1f,
                       1.4249322787e-1f, -1.6668057665e-1f, 2.0000714765e-1f,
                       -2.4999993993e-1f, 3.3333331174e-1f};
#pragma unroll
  for (int s = 0; s < 8; ++s) {
#pragma unroll
    for (int j = 0; j < 4; ++j)
      yy[j] = __fadd_rn(__fmul_rn(yy[j], m[j]), LC[s]);
  }
#pragma unroll
  for (int j = 0; j < 4; ++j) {
    yy[j] = __fmul_rn(yy[j], m[j]);
    yy[j] = __fmul_rn(yy[j], zz[j]);
    yy[j] = __fadd_rn(yy[j], __fmul_rn(e[j], -2.12194440e-4f));
    yy[j] = __fsub_rn(yy[j], __fmul_rn(zz[j], 0.5f));
    float lg = __fadd_rn(__fadd_rn(m[j], yy[j]), __fmul_rn(e[j], 0.693359375f));
    float sm = __fmul_rn(__fadd_rn(__fmul_rn(-0.5f, v[j]), 1.0f), v[j]);
    w[j] = -((fabsf(v[j]) < 1e-4f) ? sm : lg);
  }
  // ---- erfinv polynomial, coefficient-select, 4-way interleaved ----
  bool cc[4]; float qv[4], pp[4];
#pragma unroll
  for (int j = 0; j < 4; ++j) {
    cc[j] = w[j] < 5.0f;
    float qc = __fsub_rn(w[j], 2.5f);
    float qr = __fsub_rn(sqrtf(w[j]), 3.0f);
    qv[j] = cc[j] ? qc : qr;
    pp[j] = cc[j] ? 2.81022636e-08f : -0.000200214257f;
  }
  const float EA[8] = {3.43273939e-07f, -3.5233877e-06f, -4.39150654e-06f,
                       0.00021858087f, -0.00125372503f, -0.00417768164f,
                       0.246640727f, 1.50140941f};
  const float EB[8] = {0.000100950558f, 0.00134934322f, -0.00367342844f,
                       0.00573950773f, -0.0076224613f, 0.00943887047f,
                       1.00167406f, 2.83297682f};
#pragma unroll
  for (int s = 0; s < 8; ++s) {
#pragma unroll
    for (int j = 0; j < 4; ++j)
      pp[j] = __fadd_rn(__fmul_rn(pp[j], qv[j]), cc[j] ? EA[s] : EB[s]);
  }
  float nv[4];
#pragma unroll
  for (int j = 0; j < 4; ++j)
    nv[j] = __fmul_rn(1.41421356237309504880f, __fmul_rn(pp[j], xin[j]));

  // ---- y = nv * sig; normalize (sequential reduce order) ----
  float y0 = __fmul_rn(nv[0], sig0);
  float y1 = __fmul_rn(nv[1], sig1);
  float y2 = __fmul_rn(nv[2], sig2);
  float y3 = __fmul_rn(nv[3], sig3);
  float n2 = __fmul_rn(y0, y0);
  n2 = __fadd_rn(n2, __fmul_rn(y1, y1));
  n2 = __fadd_rn(n2, __fmul_rn(y2, y2));
  n2 = __fadd_rn(n2, __fmul_rn(y3, y3));
  float nr = sqrtf(n2);
  y0 = __fdiv_rn(y0, nr); y1 = __fdiv_rn(y1, nr);
  y2 = __fdiv_rn(y2, nr); y3 = __fdiv_rn(y3, nr);

  float s0q = __fmul_rn(y0, y0), s1q = __fmul_rn(y1, y1);
  float s2q = __fmul_rn(y2, y2), s3q = __fmul_rn(y3, y3);

  float s1 = __fmul_rn(s0q, 1e-6f);
  s1 = __fadd_rn(s1, __fmul_rn(s1q, lam1));
  s1 = __fadd_rn(s1, __fmul_rn(s2q, lam2));
  s1 = __fadd_rn(s1, __fmul_rn(s3q, lam3));

  float s2 = __fmul_rn(s0q, sgi0);
  s2 = __fadd_rn(s2, __fmul_rn(s1q, sgi1));
  s2 = __fadd_rn(s2, __fmul_rn(s2q, sgi2));
  s2 = __fadd_rn(s2, __fmul_rn(s3q, sgi3));

  // two independent logs, 2-way interleaved
  float lg_s2, lg_uu;
  xla_logf_pos2(s2, uu, lg_s2, lg_uu);
  float lr = __fsub_rn(-s1, 2.7725887298583984f);  // 2*f32(ln 4)
  lr = __fadd_rn(lr, 1.5f);
  lr = __fadd_rn(lr, __fmul_rn(2.0f, lg_s2));
  float lu = (uu > 0.0f) ? lg_uu : -__builtin_inff();

  accept = (lu < lr);
  ry0 = y0; ry1 = y1; ry2 = y2; ry3 = y3;
}

// ---------------------------------------------------------------------------
__global__ __launch_bounds__(256) void campose_kernel(
    const float* __restrict__ q, const float* __restrict__ Z,
    float* __restrict__ out, const int* __restrict__ seedp, int N, int C) {
  __shared__ uint4 chain[MAXT + 1];
  __shared__ uint32_t next_row;
  __shared__ uint32_t wm;   // watermark: # of published chain entries

  const int tid = threadIdx.x;
  const int rbeg = blockIdx.x * C;
  const int rend = min(N, rbeg + C);
  if (tid == 0) { next_row = (uint32_t)(rbeg + 192); wm = 0u; }
  __syncthreads();

  const int wave = tid >> 6;
  if (wave == 0) {
    // Producer: lanes 0-2 of wave 0 walk the split() chain; publish each
    // entry with a release watermark. Other waves consume concurrently.
    int lane = tid & 63;
    uint32_t ka = 0u, kb = (uint32_t)seedp[0];
    uint32_t x1i = (lane == 2) ? 0u : (uint32_t)(lane + 1);
    for (int t = 0; t < MAXT; ++t) {
      uint32_t o0 = 0u, o1 = 0u;
      if (lane < 3) tf2x32(ka, kb, 0u, x1i, o0, o1);
      uint32_t s1a = __shfl(o0, 0, 64), s1b = __shfl(o1, 0, 64);
      uint32_t s2a = __shfl(o0, 1, 64), s2b = __shfl(o1, 1, 64);
      if (lane == 0) chain[t] = make_uint4(s1a, s1b, s2a, s2b);
      ka = __shfl(o0, 2, 64); kb = __shfl(o1, 2, 64);
      __threadfence_block();
      if (lane == 0) *(volatile uint32_t*)&wm = (uint32_t)(t + 1);
    }
    if (lane == 0) chain[MAXT] = make_uint4(0u, 0u, 0u, 0u);  // prefetch pad
    __threadfence_block();
    if (lane == 0) *(volatile uint32_t*)&wm = (uint32_t)(MAXT + 1);
  }

  const float sgi0 = __fadd_rn(1.0f, __fmul_rn(2.0f, 1e-6f));
  const float sig0 = sqrtf(__fdiv_rn(1.0f, sgi0));

  // --- per-lane row state: current row r + pre-grabbed next row rn ---
  int r, rn;
  if (wave == 0) {
    r  = (int)atomicAdd(&next_row, 1u);   // producer wave joins late; queue
    rn = (int)atomicAdd(&next_row, 1u);   // auto-balances
  } else {
    r  = rbeg + (tid - 64);               // static first 192 rows
    rn = (int)atomicAdd(&next_row, 1u);
  }
  bool have = (r < rend);
  float Zn0 = 0, Zn1 = 0, Zn2 = 0;
  float4 qc = make_float4(0, 0, 0, 0), qn = make_float4(0, 0, 0, 0);
  // hoisted per-row constants for the CURRENT row
  float lam1 = 0, lam2 = 0, lam3 = 0, sgi1 = 1, sgi2 = 1, sgi3 = 1;
  float sig1 = 1, sig2 = 1, sig3 = 1;
  if (have) {
    float Z0 = Z[r * 3 + 0], Z1 = Z[r * 3 + 1], Z2 = Z[r * 3 + 2];
    lam1 = -Z0; lam2 = -Z1; lam3 = -Z2;
    sgi1 = __fadd_rn(1.0f, __fmul_rn(2.0f, lam1));
    sgi2 = __fadd_rn(1.0f, __fmul_rn(2.0f, lam2));
    sgi3 = __fadd_rn(1.0f, __fmul_rn(2.0f, lam3));
    sig1 = sqrtf(__fdiv_rn(1.0f, sgi1));
    sig2 = sqrtf(__fdiv_rn(1.0f, sgi2));
    sig3 = sqrtf(__fdiv_rn(1.0f, sgi3));
    qc = *reinterpret_cast<const float4*>(q + (size_t)r * 4);
  }
  if (rn < rend) {
    Zn0 = Z[rn * 3 + 0]; Zn1 = Z[rn * 3 + 1]; Zn2 = Z[rn * 3 + 2];
    qn = *reinterpret_cast<const float4*>(q + (size_t)rn * 4);
  }

  // wait for chain[0]; cache it (reused at every accept)
  uint32_t wml = *(volatile uint32_t*)&wm;
  while (wml < 1u) wml = *(volatile uint32_t*)&wm;
  __threadfence_block();
  const uint4 ck0 = chain[0];
  uint4 ck = ck0;
  bool chain_all = (wml >= (uint32_t)(MAXT + 1));
  int t = 0;

  while (__ballot(have)) {
    if (have) {
      // prefetch next iteration's subkeys NOW (full iteration of slack)
      if (!chain_all) {
        uint32_t need = (uint32_t)(t + 2);
        uint32_t w_ = *(volatile uint32_t*)&wm;
        while (w_ < need) w_ = *(volatile uint32_t*)&wm;
        __threadfence_block();
        chain_all = (w_ >= (uint32_t)(MAXT + 1));
      }
      uint4 ckn = chain[t + 1];

      float y0, y1, y2v, y3; bool acc;
      draw_eval(ck, (uint32_t)r, lam1, lam2, lam3,
                sgi0, sgi1, sgi2, sgi3, sig0, sig1, sig2, sig3,
                y0, y1, y2v, y3, acc);

      ++t;
      if (acc || (t >= MAXT)) {
        // inline epilogue: qn = q/||q||, out = E^T y  (q prefetched at grab)
        float a = qc.x, b = qc.y, c = qc.z, d = qc.w;
        float qn2 = __fmul_rn(a, a);
        qn2 = __fadd_rn(qn2, __fmul_rn(b, b));
        qn2 = __fadd_rn(qn2, __fmul_rn(c, c));
        qn2 = __fadd_rn(qn2, __fmul_rn(d, d));
        float qnr = sqrtf(qn2);
        a = __fdiv_rn(a, qnr); b = __fdiv_rn(b, qnr);
        c = __fdiv_rn(c, qnr); d = __fdiv_rn(d, qnr);

        float o0v = __fadd_rn(__fadd_rn(__fadd_rn(__fmul_rn(a, y0), __fmul_rn(b, y1)),
                                        __fmul_rn(c, y2v)), __fmul_rn(d, y3));
        float o1v = __fadd_rn(__fadd_rn(__fadd_rn(__fmul_rn(-b, y0), __fmul_rn(a, y1)),
                                        __fmul_rn(-d, y2v)), __fmul_rn(c, y3));
        float o2v = __fadd_rn(__fadd_rn(__fadd_rn(__fmul_rn(-c, y0), __fmul_rn(d, y1)),
                                        __fmul_rn(a, y2v)), __fmul_rn(-b, y3));
        float o3v = __fadd_rn(__fadd_rn(__fadd_rn(__fmul_rn(d, y0), __fmul_rn(c, y1)),
                                        __fmul_rn(-b, y2v)), __fmul_rn(-a, y3));
        *reinterpret_cast<float4*>(out + (size_t)r * 4) =
            make_float4(o0v, o1v, o2v, o3v);

        // rotate in the pre-grabbed row; compute its constants (same ops,
        // same order as reference -> bit-identical); pre-grab the next one
        r = rn; qc = qn;
        lam1 = -Zn0; lam2 = -Zn1; lam3 = -Zn2;
        sgi1 = __fadd_rn(1.0f, __fmul_rn(2.0f, lam1));
        sgi2 = __fadd_rn(1.0f, __fmul_rn(2.0f, lam2));
        sgi3 = __fadd_rn(1.0f, __fmul_rn(2.0f, lam3));
        sig1 = sqrtf(__fdiv_rn(1.0f, sgi1));
        sig2 = sqrtf(__fdiv_rn(1.0f, sgi2));
        sig3 = sqrtf(__fdiv_rn(1.0f, sgi3));
        t = 0;
        ck = ck0;
        have = (r < rend);
        rn = (int)atomicAdd(&next_row, 1u);
        if (rn < rend) {
          Zn0 = Z[rn * 3 + 0]; Zn1 = Z[rn * 3 + 1]; Zn2 = Z[rn * 3 + 2];
          qn = *reinterpret_cast<const float4*>(q + (size_t)rn * 4);
        }
      } else {
        ck = ckn;
      }
    }
  }
}

extern "C" void kernel_launch(void* const* d_in, const int* in_sizes, int n_in,
                              void* d_out, int out_size, void* d_ws, size_t ws_size,
                              hipStream_t stream) {
  const float* q = (const float*)d_in[0];
  const float* Z = (const float*)d_in[1];
  const int* seed = (const int*)d_in[2];
  float* out = (float*)d_out;
  int N = in_sizes[0] / 4;

  int C = (N + GRID - 1) / GRID;  // rows per block (contiguous chunk)
  campose_kernel<<<GRID, NT, 0, stream>>>(q, Z, out, seed, N, C);
}

// Round 9
// 198.523 us; speedup vs baseline: 1.0860x; 1.0273x over previous
//
#include <hip/hip_runtime.h>
#include <cstdint>

// CamPoseNet: bit-faithful JAX threefry replication (validated rounds 1-8).
// Round 9: let the scheduler USE the ILP - __launch_bounds__(256, 2).
//  R8 exposed 5 independent threefry chains + 4 erfinv chains in SoA form,
//  but VGPR stayed 44 and VALUBusy 52%: the AMDGPU backend schedules for
//  max occupancy by default and re-serialized the chains to minimize
//  register pressure. We run 2 blocks/CU (GRID=512) = 2 waves/SIMD, so
//  declare minWavesPerEU=2: pressure budget ~256 VGPR/wave, scheduler can
//  keep all chains in flight. No other change vs R8.
// All float ops on the accept-decision path use __f*_rn intrinsics (no FMA
// contraction) - matches XLA:CPU strict mul/add. Do not alter any arithmetic.

#define DEVI __device__ __forceinline__
#define MAXT 96
#define GRID 512
#define NT 256

DEVI uint32_t rotl32(uint32_t v, int s) { return (v << s) | (v >> (32 - s)); }

// Threefry-2x32, 20 rounds - single-chain version (producer wave only).
DEVI void tf2x32(uint32_t k0, uint32_t k1, uint32_t x0, uint32_t x1,
                 uint32_t& o0, uint32_t& o1) {
  const uint32_t kx = k0 ^ k1 ^ 0x1BD11BDAu;
  x0 += k0; x1 += k1;
#define TFR(r) x0 += x1; x1 = rotl32(x1, (r)); x1 ^= x0;
  TFR(13) TFR(15) TFR(26) TFR(6)
  x0 += k1; x1 += kx + 1u;
  TFR(17) TFR(29) TFR(16) TFR(24)
  x0 += kx; x1 += k0 + 2u;
  TFR(13) TFR(15) TFR(26) TFR(6)
  x0 += k0; x1 += k1 + 3u;
  TFR(17) TFR(29) TFR(16) TFR(24)
  x0 += k1; x1 += kx + 4u;
  TFR(13) TFR(15) TFR(26) TFR(6)
  x0 += kx; x1 += k0 + 5u;
#undef TFR
  o0 = x0; o1 = x1;
}

DEVI float u01_from_bits(uint32_t bits) {
  return __fsub_rn(__uint_as_float(0x3f800000u | (bits >> 9)), 1.0f);
}

// 2-wide interleaved XLA:CPU Cephes log (x > 0). Per-element ops identical
// to the scalar version - textual interleave only.
DEVI void xla_logf_pos2(float xa, float xb, float& ra, float& rb) {
  uint32_t ba = __float_as_uint(xa), bb = __float_as_uint(xb);
  float ea = (float)((int)(ba >> 23) - 126);
  float eb = (float)((int)(bb >> 23) - 126);
  float ma = __uint_as_float((ba & 0x007fffffu) | 0x3f000000u);
  float mb = __uint_as_float((bb & 0x007fffffu) | 0x3f000000u);
  bool la = ma < 0.70710678118654752440f;
  bool lb = mb < 0.70710678118654752440f;
  ea = la ? __fsub_rn(ea, 1.0f) : ea;
  eb = lb ? __fsub_rn(eb, 1.0f) : eb;
  ma = la ? __fadd_rn(__fsub_rn(ma, 1.0f), ma) : __fsub_rn(ma, 1.0f);
  mb = lb ? __fadd_rn(__fsub_rn(mb, 1.0f), mb) : __fsub_rn(mb, 1.0f);
  float za = __fmul_rn(ma, ma), zb = __fmul_rn(mb, mb);
  float ya = 7.0376836292e-2f, yb = 7.0376836292e-2f;
  const float LC[8] = {-1.1514610310e-1f, 1.1676998740e-1f, -1.2420140846e-1f,
                       1.4249322787e-1f, -1.6668057665e-1f, 2.0000714765e-1f,
                       -2.4999993993e-1f, 3.3333331174e-1f};
#pragma unroll
  for (int s = 0; s < 8; ++s) {
    ya = __fadd_rn(__fmul_rn(ya, ma), LC[s]);
    yb = __fadd_rn(__fmul_rn(yb, mb), LC[s]);
  }
  ya = __fmul_rn(ya, ma); yb = __fmul_rn(yb, mb);
  ya = __fmul_rn(ya, za); yb = __fmul_rn(yb, zb);
  ya = __fadd_rn(ya, __fmul_rn(ea, -2.12194440e-4f));
  yb = __fadd_rn(yb, __fmul_rn(eb, -2.12194440e-4f));
  ya = __fsub_rn(ya, __fmul_rn(za, 0.5f));
  yb = __fsub_rn(yb, __fmul_rn(zb, 0.5f));
  ra = __fadd_rn(__fadd_rn(ma, ya), __fmul_rn(ea, 0.693359375f));
  rb = __fadd_rn(__fadd_rn(mb, yb), __fmul_rn(eb, 0.693359375f));
}

// One full rejection draw, 5-way/4-way interleaved (SoA over chains).
// Bit-identical per element to the scalar pipeline of rounds 1-8.
DEVI void draw_eval(const uint4 ck, uint32_t r,
                    float lam1, float lam2, float lam3,
                    float sgi0, float sgi1, float sgi2, float sgi3,
                    float sig0, float sig1, float sig2, float sig3,
                    float& ry0, float& ry1, float& ry2, float& ry3,
                    bool& accept) {
  const uint32_t base = r * 4u;
  // ---- 5 interleaved threefry chains: j<4 normals (key ck.xy, ctr base+j),
  //      j==4 uniform (key ck.zw, ctr r) ----
  const uint32_t kA = ck.x, kB = ck.y, kX = kA ^ kB ^ 0x1BD11BDAu;
  const uint32_t kC = ck.z, kD = ck.w, kY = kC ^ kD ^ 0x1BD11BDAu;
  uint32_t x0[5], x1[5];
#pragma unroll
  for (int j = 0; j < 4; ++j) { x0[j] = kA; x1[j] = (base + (uint32_t)j) + kB; }
  x0[4] = kC; x1[4] = r + kD;
#define RND(rot) { \
  _Pragma("unroll") for (int j = 0; j < 5; ++j) x0[j] += x1[j]; \
  _Pragma("unroll") for (int j = 0; j < 5; ++j) x1[j] = rotl32(x1[j], rot); \
  _Pragma("unroll") for (int j = 0; j < 5; ++j) x1[j] ^= x0[j]; }
#define INJ(a0, a1, b0, b1, c) { \
  _Pragma("unroll") for (int j = 0; j < 4; ++j) { x0[j] += a0; x1[j] += b0 + c; } \
  x0[4] += a1; x1[4] += b1 + c; }
  RND(13) RND(15) RND(26) RND(6)
  INJ(kB, kD, kX, kY, 1u)
  RND(17) RND(29) RND(16) RND(24)
  INJ(kX, kY, kA, kC, 2u)
  RND(13) RND(15) RND(26) RND(6)
  INJ(kA, kC, kB, kD, 3u)
  RND(17) RND(29) RND(16) RND(24)
  INJ(kB, kD, kX, kY, 4u)
  RND(13) RND(15) RND(26) RND(6)
  INJ(kX, kY, kA, kC, 5u)
#undef RND
#undef INJ
  uint32_t bz[5];
#pragma unroll
  for (int j = 0; j < 5; ++j) bz[j] = x0[j] ^ x1[j];
  float uu = u01_from_bits(bz[4]);

  // ---- normals: u -> xin (uniform(-0.99999994, 1)) ----
  float xin[4];
#pragma unroll
  for (int j = 0; j < 4; ++j) {
    float u = u01_from_bits(bz[j]);
    float xv = __fadd_rn(__fmul_rn(u, 2.0f), -0.99999994f);
    xin[j] = fmaxf(-0.99999994f, xv);
  }

  // ---- 4-way interleaved erfinv: w = -log1p(-x^2) ----
  float v[4], w[4];
#pragma unroll
  for (int j = 0; j < 4; ++j) v[j] = -__fmul_rn(xin[j], xin[j]);
  float e[4], m[4];
#pragma unroll
  for (int j = 0; j < 4; ++j) {
    uint32_t b_ = __float_as_uint(__fadd_rn(v[j], 1.0f));
    e[j] = (float)((int)(b_ >> 23) - 126);
    m[j] = __uint_as_float((b_ & 0x007fffffu) | 0x3f000000u);
  }
#pragma unroll
  for (int j = 0; j < 4; ++j) {
    bool lt = m[j] < 0.70710678118654752440f;
    e[j] = lt ? __fsub_rn(e[j], 1.0f) : e[j];
    m[j] = lt ? __fadd_rn(__fsub_rn(m[j], 1.0f), m[j]) : __fsub_rn(m[j], 1.0f);
  }
  float zz[4], yy[4];
#pragma unroll
  for (int j = 0; j < 4; ++j) zz[j] = __fmul_rn(m[j], m[j]);
#pragma unroll
  for (int j = 0; j < 4; ++j) yy[j] = 7.0376836292e-2f;
  const float LC[8] = {-1.1514610310e-1f, 1.1676998740e-1f, -1.2420140846e-1f,
                       1.4249322787e-1f, -1.6668057665e-1f, 2.0000714765e-1f,
                       -2.4999993993e-1f, 3.3333331174e-1f};
#pragma unroll
  for (int s = 0; s < 8; ++s) {
#pragma unroll
    for (int j = 0; j < 4; ++j)
      yy[j] = __fadd_rn(__fmul_rn(yy[j], m[j]), LC[s]);
  }
#pragma unroll
  for (int j = 0; j < 4; ++j) {
    yy[j] = __fmul_rn(yy[j], m[j]);
    yy[j] = __fmul_rn(yy[j], zz[j]);
    yy[j] = __fadd_rn(yy[j], __fmul_rn(e[j], -2.12194440e-4f));
    yy[j] = __fsub_rn(yy[j], __fmul_rn(zz[j], 0.5f));
    float lg = __fadd_rn(__fadd_rn(m[j], yy[j]), __fmul_rn(e[j], 0.693359375f));
    float sm = __fmul_rn(__fadd_rn(__fmul_rn(-0.5f, v[j]), 1.0f), v[j]);
    w[j] = -((fabsf(v[j]) < 1e-4f) ? sm : lg);
  }
  // ---- erfinv polynomial, coefficient-select, 4-way interleaved ----
  bool cc[4]; float qv[4], pp[4];
#pragma unroll
  for (int j = 0; j < 4; ++j) {
    cc[j] = w[j] < 5.0f;
    float qc = __fsub_rn(w[j], 2.5f);
    float qr = __fsub_rn(sqrtf(w[j]), 3.0f);
    qv[j] = cc[j] ? qc : qr;
    pp[j] = cc[j] ? 2.81022636e-08f : -0.000200214257f;
  }
  const float EA[8] = {3.43273939e-07f, -3.5233877e-06f, -4.39150654e-06f,
                       0.00021858087f, -0.00125372503f, -0.00417768164f,
                       0.246640727f, 1.50140941f};
  const float EB[8] = {0.000100950558f, 0.00134934322f, -0.00367342844f,
                       0.00573950773f, -0.0076224613f, 0.00943887047f,
                       1.00167406f, 2.83297682f};
#pragma unroll
  for (int s = 0; s < 8; ++s) {
#pragma unroll
    for (int j = 0; j < 4; ++j)
      pp[j] = __fadd_rn(__fmul_rn(pp[j], qv[j]), cc[j] ? EA[s] : EB[s]);
  }
  float nv[4];
#pragma unroll
  for (int j = 0; j < 4; ++j)
    nv[j] = __fmul_rn(1.41421356237309504880f, __fmul_rn(pp[j], xin[j]));

  // ---- y = nv * sig; normalize (sequential reduce order) ----
  float y0 = __fmul_rn(nv[0], sig0);
  float y1 = __fmul_rn(nv[1], sig1);
  float y2 = __fmul_rn(nv[2], sig2);
  float y3 = __fmul_rn(nv[3], sig3);
  float n2 = __fmul_rn(y0, y0);
  n2 = __fadd_rn(n2, __fmul_rn(y1, y1));
  n2 = __fadd_rn(n2, __fmul_rn(y2, y2));
  n2 = __fadd_rn(n2, __fmul_rn(y3, y3));
  float nr = sqrtf(n2);
  y0 = __fdiv_rn(y0, nr); y1 = __fdiv_rn(y1, nr);
  y2 = __fdiv_rn(y2, nr); y3 = __fdiv_rn(y3, nr);

  float s0q = __fmul_rn(y0, y0), s1q = __fmul_rn(y1, y1);
  float s2q = __fmul_rn(y2, y2), s3q = __fmul_rn(y3, y3);

  float s1 = __fmul_rn(s0q, 1e-6f);
  s1 = __fadd_rn(s1, __fmul_rn(s1q, lam1));
  s1 = __fadd_rn(s1, __fmul_rn(s2q, lam2));
  s1 = __fadd_rn(s1, __fmul_rn(s3q, lam3));

  float s2 = __fmul_rn(s0q, sgi0);
  s2 = __fadd_rn(s2, __fmul_rn(s1q, sgi1));
  s2 = __fadd_rn(s2, __fmul_rn(s2q, sgi2));
  s2 = __fadd_rn(s2, __fmul_rn(s3q, sgi3));

  // two independent logs, 2-way interleaved
  float lg_s2, lg_uu;
  xla_logf_pos2(s2, uu, lg_s2, lg_uu);
  float lr = __fsub_rn(-s1, 2.7725887298583984f);  // 2*f32(ln 4)
  lr = __fadd_rn(lr, 1.5f);
  lr = __fadd_rn(lr, __fmul_rn(2.0f, lg_s2));
  float lu = (uu > 0.0f) ? lg_uu : -__builtin_inff();

  accept = (lu < lr);
  ry0 = y0; ry1 = y1; ry2 = y2; ry3 = y3;
}

// ---------------------------------------------------------------------------
// minWavesPerEU=2: we run exactly 2 waves/SIMD (GRID=512, 2 blocks/CU).
// This raises the backend's register-pressure budget to ~256 VGPR/wave so
// the machine scheduler keeps the independent chains in flight instead of
// serializing them for (unused) occupancy.
__global__ __launch_bounds__(256, 2) void campose_kernel(
    const float* __restrict__ q, const float* __restrict__ Z,
    float* __restrict__ out, const int* __restrict__ seedp, int N, int C) {
  __shared__ uint4 chain[MAXT + 1];
  __shared__ uint32_t next_row;
  __shared__ uint32_t wm;   // watermark: # of published chain entries

  const int tid = threadIdx.x;
  const int rbeg = blockIdx.x * C;
  const int rend = min(N, rbeg + C);
  if (tid == 0) { next_row = (uint32_t)(rbeg + 192); wm = 0u; }
  __syncthreads();

  const int wave = tid >> 6;
  if (wave == 0) {
    // Producer: lanes 0-2 of wave 0 walk the split() chain; publish each
    // entry with a release watermark. Other waves consume concurrently.
    int lane = tid & 63;
    uint32_t ka = 0u, kb = (uint32_t)seedp[0];
    uint32_t x1i = (lane == 2) ? 0u : (uint32_t)(lane + 1);
    for (int t = 0; t < MAXT; ++t) {
      uint32_t o0 = 0u, o1 = 0u;
      if (lane < 3) tf2x32(ka, kb, 0u, x1i, o0, o1);
      uint32_t s1a = __shfl(o0, 0, 64), s1b = __shfl(o1, 0, 64);
      uint32_t s2a = __shfl(o0, 1, 64), s2b = __shfl(o1, 1, 64);
      if (lane == 0) chain[t] = make_uint4(s1a, s1b, s2a, s2b);
      ka = __shfl(o0, 2, 64); kb = __shfl(o1, 2, 64);
      __threadfence_block();
      if (lane == 0) *(volatile uint32_t*)&wm = (uint32_t)(t + 1);
    }
    if (lane == 0) chain[MAXT] = make_uint4(0u, 0u, 0u, 0u);  // prefetch pad
    __threadfence_block();
    if (lane == 0) *(volatile uint32_t*)&wm = (uint32_t)(MAXT + 1);
  }

  const float sgi0 = __fadd_rn(1.0f, __fmul_rn(2.0f, 1e-6f));
  const float sig0 = sqrtf(__fdiv_rn(1.0f, sgi0));

  // --- per-lane row state: current row r + pre-grabbed next row rn ---
  int r, rn;
  if (wave == 0) {
    r  = (int)atomicAdd(&next_row, 1u);   // producer wave joins late; queue
    rn = (int)atomicAdd(&next_row, 1u);   // auto-balances
  } else {
    r  = rbeg + (tid - 64);               // static first 192 rows
    rn = (int)atomicAdd(&next_row, 1u);
  }
  bool have = (r < rend);
  float Zn0 = 0, Zn1 = 0, Zn2 = 0;
  float4 qc = make_float4(0, 0, 0, 0), qn = make_float4(0, 0, 0, 0);
  // hoisted per-row constants for the CURRENT row
  float lam1 = 0, lam2 = 0, lam3 = 0, sgi1 = 1, sgi2 = 1, sgi3 = 1;
  float sig1 = 1, sig2 = 1, sig3 = 1;
  if (have) {
    float Z0 = Z[r * 3 + 0], Z1 = Z[r * 3 + 1], Z2 = Z[r * 3 + 2];
    lam1 = -Z0; lam2 = -Z1; lam3 = -Z2;
    sgi1 = __fadd_rn(1.0f, __fmul_rn(2.0f, lam1));
    sgi2 = __fadd_rn(1.0f, __fmul_rn(2.0f, lam2));
    sgi3 = __fadd_rn(1.0f, __fmul_rn(2.0f, lam3));
    sig1 = sqrtf(__fdiv_rn(1.0f, sgi1));
    sig2 = sqrtf(__fdiv_rn(1.0f, sgi2));
    sig3 = sqrtf(__fdiv_rn(1.0f, sgi3));
    qc = *reinterpret_cast<const float4*>(q + (size_t)r * 4);
  }
  if (rn < rend) {
    Zn0 = Z[rn * 3 + 0]; Zn1 = Z[rn * 3 + 1]; Zn2 = Z[rn * 3 + 2];
    qn = *reinterpret_cast<const float4*>(q + (size_t)rn * 4);
  }

  // wait for chain[0]; cache it (reused at every accept)
  uint32_t wml = *(volatile uint32_t*)&wm;
  while (wml < 1u) wml = *(volatile uint32_t*)&wm;
  __threadfence_block();
  const uint4 ck0 = chain[0];
  uint4 ck = ck0;
  bool chain_all = (wml >= (uint32_t)(MAXT + 1));
  int t = 0;

  while (__ballot(have)) {
    if (have) {
      // prefetch next iteration's subkeys NOW (full iteration of slack)
      if (!chain_all) {
        uint32_t need = (uint32_t)(t + 2);
        uint32_t w_ = *(volatile uint32_t*)&wm;
        while (w_ < need) w_ = *(volatile uint32_t*)&wm;
        __threadfence_block();
        chain_all = (w_ >= (uint32_t)(MAXT + 1));
      }
      uint4 ckn = chain[t + 1];

      float y0, y1, y2v, y3; bool acc;
      draw_eval(ck, (uint32_t)r, lam1, lam2, lam3,
                sgi0, sgi1, sgi2, sgi3, sig0, sig1, sig2, sig3,
                y0, y1, y2v, y3, acc);

      ++t;
      if (acc || (t >= MAXT)) {
        // inline epilogue: qn = q/||q||, out = E^T y  (q prefetched at grab)
        float a = qc.x, b = qc.y, c = qc.z, d = qc.w;
        float qn2 = __fmul_rn(a, a);
        qn2 = __fadd_rn(qn2, __fmul_rn(b, b));
        qn2 = __fadd_rn(qn2, __fmul_rn(c, c));
        qn2 = __fadd_rn(qn2, __fmul_rn(d, d));
        float qnr = sqrtf(qn2);
        a = __fdiv_rn(a, qnr); b = __fdiv_rn(b, qnr);
        c = __fdiv_rn(c, qnr); d = __fdiv_rn(d, qnr);

        float o0v = __fadd_rn(__fadd_rn(__fadd_rn(__fmul_rn(a, y0), __fmul_rn(b, y1)),
                                        __fmul_rn(c, y2v)), __fmul_rn(d, y3));
        float o1v = __fadd_rn(__fadd_rn(__fadd_rn(__fmul_rn(-b, y0), __fmul_rn(a, y1)),
                                        __fmul_rn(-d, y2v)), __fmul_rn(c, y3));
        float o2v = __fadd_rn(__fadd_rn(__fadd_rn(__fmul_rn(-c, y0), __fmul_rn(d, y1)),
                                        __fmul_rn(a, y2v)), __fmul_rn(-b, y3));
        float o3v = __fadd_rn(__fadd_rn(__fadd_rn(__fmul_rn(d, y0), __fmul_rn(c, y1)),
                                        __fmul_rn(-b, y2v)), __fmul_rn(-a, y3));
        *reinterpret_cast<float4*>(out + (size_t)r * 4) =
            make_float4(o0v, o1v, o2v, o3v);

        // rotate in the pre-grabbed row; compute its constants (same ops,
        // same order as reference -> bit-identical); pre-grab the next one
        r = rn; qc = qn;
        lam1 = -Zn0; lam2 = -Zn1; lam3 = -Zn2;
        sgi1 = __fadd_rn(1.0f, __fmul_rn(2.0f, lam1));
        sgi2 = __fadd_rn(1.0f, __fmul_rn(2.0f, lam2));
        sgi3 = __fadd_rn(1.0f, __fmul_rn(2.0f, lam3));
        sig1 = sqrtf(__fdiv_rn(1.0f, sgi1));
        sig2 = sqrtf(__fdiv_rn(1.0f, sgi2));
        sig3 = sqrtf(__fdiv_rn(1.0f, sgi3));
        t = 0;
        ck = ck0;
        have = (r < rend);
        rn = (int)atomicAdd(&next_row, 1u);
        if (rn < rend) {
          Zn0 = Z[rn * 3 + 0]; Zn1 = Z[rn * 3 + 1]; Zn2 = Z[rn * 3 + 2];
          qn = *reinterpret_cast<const float4*>(q + (size_t)rn * 4);
        }
      } else {
        ck = ckn;
      }
    }
  }
}

extern "C" void kernel_launch(void* const* d_in, const int* in_sizes, int n_in,
                              void* d_out, int out_size, void* d_ws, size_t ws_size,
                              hipStream_t stream) {
  const float* q = (const float*)d_in[0];
  const float* Z = (const float*)d_in[1];
  const int* seed = (const int*)d_in[2];
  float* out = (float*)d_out;
  int N = in_sizes[0] / 4;

  int C = (N + GRID - 1) / GRID;  // rows per block (contiguous chunk)
  campose_kernel<<<GRID, NT, 0, stream>>>(q, Z, out, seed, N, C);
}